// Round 2
// baseline (160.097 us; speedup 1.0000x reference)
//
#include <hip/hip_runtime.h>
#include <stdint.h>

// Problem constants (fixed by the reference)
#define BATCH   4096
#define IN_DIM  1024
#define OUT_DIM 1024

typedef __bf16 bf16x8 __attribute__((ext_vector_type(8)));
typedef float  f32x4  __attribute__((ext_vector_type(4)));

// fp32 -> bf16 bits, round-to-nearest-even
__device__ __forceinline__ uint16_t f2bf(float f) {
    union { float f; uint32_t u; } v; v.f = f;
    uint32_t u = v.u;
    uint32_t r = (u + 0x7FFFu + ((u >> 16) & 1u)) >> 16;
    return (uint16_t)r;
}

// ---------------------------------------------------------------------------
// prep: blocks 0..4095    -> convert x row b to bf16; compute alpha[b][0..3];
//                            pre-fill out[b,:] = sum_c alpha_c * bias[c,:]
//       blocks 4096..8191 -> convert W (flat 4M floats) to bf16
// The out pre-fill replaces both the reduce kernel's bias term and a memset:
// the gemm then just atomically adds alpha_c * (x . W_c^T).
// ---------------------------------------------------------------------------
__global__ __launch_bounds__(256) void prep(
    const float* __restrict__ x, const float* __restrict__ phase,
    const float* __restrict__ basis, const float* __restrict__ W,
    const float* __restrict__ biases,
    uint16_t* __restrict__ xb, uint16_t* __restrict__ Wb,
    float* __restrict__ alphaWS, float* __restrict__ out)
{
    const int bid = blockIdx.x;
    const int tid = threadIdx.x;

    if (bid < BATCH) {
        const int b = bid;
        const float HALF_PI = 1.5707963267948966f;
        float s  = phase[b] / HALF_PI;
        int   q  = (int)floorf(s);
        q = q < 0 ? 0 : (q > 3 ? 3 : q);
        float t  = s - (float)q;
        float t2 = t * t, t3 = t2 * t;

        float coef[4];
#pragma unroll
        for (int j = 0; j < 4; ++j)
            coef[j] = t3 * basis[j] + t2 * basis[4 + j] + t * basis[8 + j] + basis[12 + j];

        // CPI[q][k] = (q+k+3)%4  =>  alpha[c] = coef[(c - q + 1) & 3]
        float alpha[4];
#pragma unroll
        for (int c = 0; c < 4; ++c)
            alpha[c] = coef[(c - q + 1) & 3];

        if (tid < 4) alphaWS[b * 4 + tid] = alpha[tid];

        // x row -> bf16
        float4 xv = ((const float4*)(x + (size_t)b * IN_DIM))[tid];
        ushort4 o;
        o.x = f2bf(xv.x); o.y = f2bf(xv.y); o.z = f2bf(xv.z); o.w = f2bf(xv.w);
        ((ushort4*)(xb + (size_t)b * IN_DIM))[tid] = o;

        // out[b,:] = sum_c alpha_c * bias[c,:]   (bias is tiny, L2-hot)
        float4 acc = {0.f, 0.f, 0.f, 0.f};
#pragma unroll
        for (int c = 0; c < 4; ++c) {
            float4 bv = ((const float4*)(biases + (size_t)c * OUT_DIM))[tid];
            acc.x += alpha[c] * bv.x;
            acc.y += alpha[c] * bv.y;
            acc.z += alpha[c] * bv.z;
            acc.w += alpha[c] * bv.w;
        }
        ((float4*)(out + (size_t)b * OUT_DIM))[tid] = acc;
    } else {
        const int j = bid - BATCH;                 // 0..4095, W has 1M float4s
        float4 wv = ((const float4*)W)[j * 256 + tid];
        ushort4 o;
        o.x = f2bf(wv.x); o.y = f2bf(wv.y); o.z = f2bf(wv.z); o.w = f2bf(wv.w);
        ((ushort4*)Wb)[j * 256 + tid] = o;
    }
}

// ---------------------------------------------------------------------------
// gemm_split: out[m,n] += alpha[m,c] * sum_k x[m,k] * W[c,n,k]   (K = 1024)
// Proven round-0 main loop: 128x128 tile, BK=64, 256 threads (2x2 waves,
// each 64x64 via 4x4 MFMA). grid = (32 M, 8 N, 4 c) = 1024 blocks -> 4/CU.
// The 4 c-blocks of a tile are 256 apart in linear id -> same XCD/CU bucket:
// shared A-tile is L2-local and their epilogues are time-skewed (low atomic
// contention). Epilogue: fp32 atomicAdd with alpha applied per row — removes
// the bf16 P intermediate (32 MB) and the entire reduce kernel (48 MB + launch).
// LDS XOR swizzle on the global source address (global_load_lds dest is
// lane-contiguous); read side chunk = (ks*4 + quad) ^ (lane&7).
// ---------------------------------------------------------------------------
__global__ __launch_bounds__(256, 4) void gemm_split(
    const uint16_t* __restrict__ xb, const uint16_t* __restrict__ Wb,
    const float* __restrict__ alphaWS, float* __restrict__ out)
{
    __shared__ uint16_t As[128 * 64];
    __shared__ uint16_t Bs[128 * 64];

    const int tid  = threadIdx.x;
    const int lane = tid & 63;
    const int wid  = tid >> 6;
    const int wm   = wid >> 1;
    const int wn   = wid & 1;
    const int tileM = blockIdx.x * 128;
    const int tileN = blockIdx.y * 128;
    const int c     = blockIdx.z;

    f32x4 acc[4][4];
#pragma unroll
    for (int mi = 0; mi < 4; ++mi)
#pragma unroll
        for (int ni = 0; ni < 4; ++ni)
            acc[mi][ni] = (f32x4){0.f, 0.f, 0.f, 0.f};

    // staging: slice s (=wid*4+j) covers rows 8s..8s+7; lane l -> row l>>3,
    // physical chunk l&7; source global chunk = (l&7) ^ (l>>3)  (XOR swizzle)
    const int srow = lane >> 3;
    const int gchunk = ((lane & 7) ^ srow) * 8;   // element offset of 8-elem chunk

    const uint16_t* Ag = xb + (size_t)tileM * 1024;
    const uint16_t* Bg = Wb + ((size_t)c << 20) + (size_t)tileN * 1024;

    const int quad = lane >> 4;
    const int l7   = lane & 7;

    for (int kt = 0; kt < 16; ++kt) {
        const int k0 = kt * 64;
#pragma unroll
        for (int j = 0; j < 4; ++j) {
            const int s = wid * 4 + j;
            const uint16_t* ga = Ag + (size_t)(s * 8 + srow) * 1024 + k0 + gchunk;
            __builtin_amdgcn_global_load_lds(
                (const __attribute__((address_space(1))) void*)ga,
                (__attribute__((address_space(3))) void*)(As + s * 512), 16, 0, 0);
            const uint16_t* gb = Bg + (size_t)(s * 8 + srow) * 1024 + k0 + gchunk;
            __builtin_amdgcn_global_load_lds(
                (const __attribute__((address_space(1))) void*)gb,
                (__attribute__((address_space(3))) void*)(Bs + s * 512), 16, 0, 0);
        }
        __syncthreads();

#pragma unroll
        for (int ks = 0; ks < 2; ++ks) {
            bf16x8 af[4], bfr[4];
#pragma unroll
            for (int mi = 0; mi < 4; ++mi) {
                const int row = wm * 64 + mi * 16 + (lane & 15);
                const int ch  = (ks * 4 + quad) ^ l7;     // physical chunk
                af[mi] = *(const bf16x8*)(As + row * 64 + ch * 8);
            }
#pragma unroll
            for (int ni = 0; ni < 4; ++ni) {
                const int row = wn * 64 + ni * 16 + (lane & 15);
                const int ch  = (ks * 4 + quad) ^ l7;
                bfr[ni] = *(const bf16x8*)(Bs + row * 64 + ch * 8);
            }
#pragma unroll
            for (int mi = 0; mi < 4; ++mi)
#pragma unroll
                for (int ni = 0; ni < 4; ++ni)
                    acc[mi][ni] = __builtin_amdgcn_mfma_f32_16x16x32_bf16(
                        af[mi], bfr[ni], acc[mi][ni], 0, 0, 0);
        }
        __syncthreads();
    }

    // Epilogue: out[m,n] += alpha[m,c] * acc
    // C/D layout: col = lane&15, row = quad*4 + reg  [m89/m91 verified]
    const int col0 = tileN + wn * 64 + (lane & 15);
#pragma unroll
    for (int mi = 0; mi < 4; ++mi) {
#pragma unroll
        for (int r = 0; r < 4; ++r) {
            const int m  = tileM + wm * 64 + mi * 16 + quad * 4 + r;
            const float al = alphaWS[m * 4 + c];   // broadcast within 16-lane group
#pragma unroll
            for (int ni = 0; ni < 4; ++ni) {
                __hip_atomic_fetch_add(
                    &out[(size_t)m * OUT_DIM + col0 + ni * 16],
                    al * acc[mi][ni][r],
                    __ATOMIC_RELAXED, __HIP_MEMORY_SCOPE_AGENT);
            }
        }
    }
}

extern "C" void kernel_launch(void* const* d_in, const int* in_sizes, int n_in,
                              void* d_out, int out_size, void* d_ws, size_t ws_size,
                              hipStream_t stream)
{
    const float* x       = (const float*)d_in[0];  // (B, IN)
    const float* phase   = (const float*)d_in[1];  // (B,)
    const float* weights = (const float*)d_in[2];  // (4, OUT, IN)
    const float* biases  = (const float*)d_in[3];  // (4, OUT)
    const float* basis   = (const float*)d_in[4];  // (4, 4)
    float* out = (float*)d_out;                    // (B, OUT)

    // Workspace: xb bf16 8 MB | Wb bf16 8 MB | alpha 64 KB
    uint16_t* xb = (uint16_t*)d_ws;
    uint16_t* Wb = xb + (size_t)BATCH * IN_DIM;
    float* alphaWS = (float*)(Wb + (size_t)4 * OUT_DIM * IN_DIM);

    prep<<<2 * BATCH, 256, 0, stream>>>(x, phase, basis, weights, biases,
                                        xb, Wb, alphaWS, out);

    dim3 grid(BATCH / 128, OUT_DIM / 128, 4);  // M fastest for XCD L2 locality
    gemm_split<<<grid, 256, 0, stream>>>(xb, Wb, alphaWS, out);
}